// Round 4
// baseline (118.746 us; speedup 1.0000x reference)
//
#include <hip/hip_runtime.h>
#include <math.h>

#define SD 39
#define BLOCK 256

__global__ __launch_bounds__(BLOCK, 4) void qnet_kernel(
    const float* __restrict__ state,
    const float* __restrict__ ew1, const float* __restrict__ eb1,
    const float* __restrict__ ew2, const float* __restrict__ eb2,
    const float* __restrict__ ew3, const float* __restrict__ eb3,
    const float* __restrict__ qp,
    const float* __restrict__ dw1, const float* __restrict__ db1,
    const float* __restrict__ dw2, const float* __restrict__ db2,
    const float* __restrict__ dw3, const float* __restrict__ db3,
    float* __restrict__ out, int nrows_total)
{
    __shared__ __align__(16) float tile[BLOCK * SD];
    const int tid = threadIdx.x;
    const long long b0 = (long long)blockIdx.x * BLOCK;
    const int rows = (int)min((long long)BLOCK, (long long)nrows_total - b0);
    const float* src = state + b0 * SD;

    if (rows == BLOCK) {                       // block-uniform branch
        // 256*39 floats = 2496 float4; 256 threads -> 10 strided iters.
        const float4* s4 = (const float4*)src;
        float4* t4 = (float4*)tile;
        #pragma unroll 2
        for (int i = tid; i < (BLOCK * SD) / 4; i += BLOCK) t4[i] = s4[i];
    } else {
        for (int i = tid; i < rows * SD; i += BLOCK) tile[i] = src[i];
    }
    __syncthreads();

    // NO early return: keep control flow wave-uniform so weight loads
    // scalarize to s_load (SGPR operands). Clamp the row index instead;
    // only the final store is predicated.
    const int r = (tid < rows) ? tid : (rows - 1);

    // row into registers; asm launder pins each value in a VGPR so the
    // compiler cannot rematerialize it as an LDS re-read inside the
    // unrolled FMA region.
    float s[SD];
    #pragma unroll
    for (int i = 0; i < SD; i++) {
        s[i] = tile[r * SD + i];
        asm volatile("" : "+v"(s[i]));
    }

    // ---- FUSED encoder layers 1+2: 39 -> 64 -> 32 ----
    float acc2[32];
    #pragma unroll
    for (int o = 0; o < 32; o++) acc2[o] = eb2[o];

    #pragma unroll 4
    for (int o1 = 0; o1 < 64; o1++) {
        float a = eb1[o1];
        const float* w1 = ew1 + o1 * SD;       // uniform -> s_load
        #pragma unroll
        for (int i = 0; i < SD; i++) a = fmaf(s[i], w1[i], a);
        a = fmaxf(a, 0.0f);
        #pragma unroll
        for (int o2 = 0; o2 < 32; o2++)
            acc2[o2] = fmaf(a, ew2[o2 * 64 + o1], acc2[o2]);
    }

    float h2[32];
    #pragma unroll
    for (int o = 0; o < 32; o++) h2[o] = fmaxf(acc2[o], 0.0f);

    // ---- encoder layer 3: 32 -> 4, fast tanh; analytic quantum expvals ----
    // ev_i = prod_{j<=i} cos(enc_j*pi + qp[2j])  (RZ cancels under Z-measure;
    // CNOT chain -> bit i = b0^..^bi; independence factorizes expectation)
    float ev[4];
    float cprod = 1.0f;
    #pragma unroll
    for (int o = 0; o < 4; o++) {
        float acc = eb3[o];
        const float* w = ew3 + o * 32;
        #pragma unroll
        for (int i = 0; i < 32; i++) acc = fmaf(h2[i], w[i], acc);
        // tanh(x) = 1 - 2/(e^{2x}+1); exact at +-inf saturation
        float e = __expf(2.0f * acc);
        float enc = 1.0f - 2.0f / (e + 1.0f);
        float theta = fmaf(enc, 3.14159265358979323846f, qp[2 * o]);
        cprod *= __cosf(theta);
        ev[o] = cprod;
    }

    // ---- decoder layer 1: 4 -> 32, ReLU ----
    float d1[32];
    #pragma unroll 4
    for (int o = 0; o < 32; o++) {
        float acc = db1[o];
        const float* w = dw1 + o * 4;
        #pragma unroll
        for (int i = 0; i < 4; i++) acc = fmaf(ev[i], w[i], acc);
        d1[o] = fmaxf(acc, 0.0f);
    }

    // ---- decoder layer 2: 32 -> 16, ReLU ----
    float d2[16];
    #pragma unroll 4
    for (int o = 0; o < 16; o++) {
        float acc = db2[o];
        const float* w = dw2 + o * 32;
        #pragma unroll
        for (int i = 0; i < 32; i++) acc = fmaf(d1[i], w[i], acc);
        d2[o] = fmaxf(acc, 0.0f);
    }

    // ---- decoder layer 3: 16 -> 8, linear ----
    float o8[8];
    #pragma unroll
    for (int o = 0; o < 8; o++) {
        float acc = db3[o];
        const float* w = dw3 + o * 16;
        #pragma unroll
        for (int i = 0; i < 16; i++) acc = fmaf(d2[i], w[i], acc);
        o8[o] = acc;
    }

    if (tid < rows) {                          // only the store is predicated
        float4* op = (float4*)(out + (b0 + tid) * 8);
        op[0] = make_float4(o8[0], o8[1], o8[2], o8[3]);
        op[1] = make_float4(o8[4], o8[5], o8[6], o8[7]);
    }
}

extern "C" void kernel_launch(void* const* d_in, const int* in_sizes, int n_in,
                              void* d_out, int out_size, void* d_ws, size_t ws_size,
                              hipStream_t stream) {
    const float* state = (const float*)d_in[0];
    const float* ew1 = (const float*)d_in[1];
    const float* eb1 = (const float*)d_in[2];
    const float* ew2 = (const float*)d_in[3];
    const float* eb2 = (const float*)d_in[4];
    const float* ew3 = (const float*)d_in[5];
    const float* eb3 = (const float*)d_in[6];
    const float* qp  = (const float*)d_in[7];
    const float* dw1 = (const float*)d_in[8];
    const float* db1 = (const float*)d_in[9];
    const float* dw2 = (const float*)d_in[10];
    const float* db2 = (const float*)d_in[11];
    const float* dw3 = (const float*)d_in[12];
    const float* db3 = (const float*)d_in[13];
    float* out = (float*)d_out;

    const int B = in_sizes[0] / SD;
    const int grid = (B + BLOCK - 1) / BLOCK;
    hipLaunchKernelGGL(qnet_kernel, dim3(grid), dim3(BLOCK), 0, stream,
                       state, ew1, eb1, ew2, eb2, ew3, eb3, qp,
                       dw1, db1, dw2, db2, dw3, db3, out, B);
}

// Round 5
// 70.698 us; speedup vs baseline: 1.6796x; 1.6796x over previous
//
#include <hip/hip_runtime.h>
#include <math.h>

#define SD 39
#define BLOCK 256

__global__ __launch_bounds__(BLOCK)
__attribute__((amdgpu_waves_per_eu(2, 4)))   // LDS caps us at 4 waves/SIMD;
                                             // stop the scheduler from
                                             // register-squeezing for 8+.
void qnet_kernel(
    const float* __restrict__ state,
    const float* __restrict__ ew1, const float* __restrict__ eb1,
    const float* __restrict__ ew2, const float* __restrict__ eb2,
    const float* __restrict__ ew3, const float* __restrict__ eb3,
    const float* __restrict__ qp,
    const float* __restrict__ dw1, const float* __restrict__ db1,
    const float* __restrict__ dw2, const float* __restrict__ db2,
    const float* __restrict__ dw3, const float* __restrict__ db3,
    float* __restrict__ out, int nrows_total)
{
    __shared__ __align__(16) float tile[BLOCK * SD];
    const int tid = threadIdx.x;
    const long long b0 = (long long)blockIdx.x * BLOCK;
    const int rows = (int)min((long long)BLOCK, (long long)nrows_total - b0);
    const float* src = state + b0 * SD;

    if (rows == BLOCK) {
        // 256*39 floats = 2496 float4; 256 threads -> 10 strided iters.
        const float4* s4 = (const float4*)src;
        float4* t4 = (float4*)tile;
        #pragma unroll 2
        for (int i = tid; i < (BLOCK * SD) / 4; i += BLOCK) t4[i] = s4[i];
    } else {
        for (int i = tid; i < rows * SD; i += BLOCK) tile[i] = src[i];
    }
    __syncthreads();

    if (tid >= rows) return;

    // row into registers (stride-39 LDS reads: spread across banks, ~free)
    float s[SD];
    #pragma unroll
    for (int i = 0; i < SD; i++) s[i] = tile[tid * SD + i];

    // ---- FUSED encoder layers 1+2: 39 -> 64 -> 32 ----
    // h1 never materialized; each h1 value immediately folded into the 32
    // layer-2 accumulators. Peak live ~= s[39] + acc2[32] ~ 85 VGPRs.
    float acc2[32];
    #pragma unroll
    for (int o = 0; o < 32; o++) acc2[o] = eb2[o];

    #pragma unroll 4
    for (int o1 = 0; o1 < 64; o1++) {
        float a = eb1[o1];
        const float* w1 = ew1 + o1 * SD;       // uniform address -> s_load
        #pragma unroll
        for (int i = 0; i < SD; i++) a = fmaf(s[i], w1[i], a);
        a = fmaxf(a, 0.0f);
        #pragma unroll
        for (int o2 = 0; o2 < 32; o2++)
            acc2[o2] = fmaf(a, ew2[o2 * 64 + o1], acc2[o2]);
    }

    float h2[32];
    #pragma unroll
    for (int o = 0; o < 32; o++) h2[o] = fmaxf(acc2[o], 0.0f);

    // ---- encoder layer 3: 32 -> 4, fast tanh; analytic quantum expvals ----
    // ev_i = prod_{j<=i} cos(enc_j*pi + qp[2j])  (RZ cancels under Z-measure;
    // CNOT chain -> bit i = b0^..^bi; independence factorizes expectation)
    float ev[4];
    float cprod = 1.0f;
    #pragma unroll
    for (int o = 0; o < 4; o++) {
        float acc = eb3[o];
        const float* w = ew3 + o * 32;
        #pragma unroll
        for (int i = 0; i < 32; i++) acc = fmaf(h2[i], w[i], acc);
        // tanh(x) = 1 - 2/(e^{2x}+1); exact at +-inf saturation
        float e = __expf(2.0f * acc);
        float enc = 1.0f - 2.0f / (e + 1.0f);
        float theta = fmaf(enc, 3.14159265358979323846f, qp[2 * o]);
        cprod *= __cosf(theta);
        ev[o] = cprod;
    }

    // ---- decoder layer 1: 4 -> 32, ReLU ----
    float d1[32];
    #pragma unroll 4
    for (int o = 0; o < 32; o++) {
        float acc = db1[o];
        const float* w = dw1 + o * 4;
        #pragma unroll
        for (int i = 0; i < 4; i++) acc = fmaf(ev[i], w[i], acc);
        d1[o] = fmaxf(acc, 0.0f);
    }

    // ---- decoder layer 2: 32 -> 16, ReLU ----
    float d2[16];
    #pragma unroll 4
    for (int o = 0; o < 16; o++) {
        float acc = db2[o];
        const float* w = dw2 + o * 32;
        #pragma unroll
        for (int i = 0; i < 32; i++) acc = fmaf(d1[i], w[i], acc);
        d2[o] = fmaxf(acc, 0.0f);
    }

    // ---- decoder layer 3: 16 -> 8, linear; vectorized store ----
    float o8[8];
    #pragma unroll
    for (int o = 0; o < 8; o++) {
        float acc = db3[o];
        const float* w = dw3 + o * 16;
        #pragma unroll
        for (int i = 0; i < 16; i++) acc = fmaf(d2[i], w[i], acc);
        o8[o] = acc;
    }
    float4* op = (float4*)(out + (b0 + tid) * 8);
    op[0] = make_float4(o8[0], o8[1], o8[2], o8[3]);
    op[1] = make_float4(o8[4], o8[5], o8[6], o8[7]);
}

extern "C" void kernel_launch(void* const* d_in, const int* in_sizes, int n_in,
                              void* d_out, int out_size, void* d_ws, size_t ws_size,
                              hipStream_t stream) {
    const float* state = (const float*)d_in[0];
    const float* ew1 = (const float*)d_in[1];
    const float* eb1 = (const float*)d_in[2];
    const float* ew2 = (const float*)d_in[3];
    const float* eb2 = (const float*)d_in[4];
    const float* ew3 = (const float*)d_in[5];
    const float* eb3 = (const float*)d_in[6];
    const float* qp  = (const float*)d_in[7];
    const float* dw1 = (const float*)d_in[8];
    const float* db1 = (const float*)d_in[9];
    const float* dw2 = (const float*)d_in[10];
    const float* db2 = (const float*)d_in[11];
    const float* dw3 = (const float*)d_in[12];
    const float* db3 = (const float*)d_in[13];
    float* out = (float*)d_out;

    const int B = in_sizes[0] / SD;
    const int grid = (B + BLOCK - 1) / BLOCK;
    hipLaunchKernelGGL(qnet_kernel, dim3(grid), dim3(BLOCK), 0, stream,
                       state, ew1, eb1, ew2, eb2, ew3, eb3, qp,
                       dw1, db1, dw2, db2, dw3, db3, out, B);
}